// Round 3
// baseline (108.930 us; speedup 1.0000x reference)
//
#include <hip/hip_runtime.h>

// 3D Haar DWT, fixed size: x[N=4, C=4, D=64, H=256, W=256] f32.
// Outputs: 8 bands (LLL..HHH), each [4,4,32,128,128], concat flat in d_out.
// Band bit2=D-high, bit1=H-high, bit0=W-high; low=a+b, high=a-b per axis,
// total scale 2^-1.5.
//
// One thread = FOUR adjacent output columns: 8x float4 nontemporal loads
// (2 per row x 4 rows of the 2x2x2 cubes), 8x float4 nontemporal stores
// (one per band). 16 B/lane both directions; streaming, no cache reuse.
// Native clang vector type: __builtin_nontemporal_* rejects HIP_vector_type.

typedef float f32x4 __attribute__((ext_vector_type(4)));

#define S3 0.35355339059327378f  // 2^-1.5

__global__ __launch_bounds__(256) void dwt3d_haar_kernel(
    const float* __restrict__ x, float* __restrict__ out) {
  // total threads = N*C * D/2 * H/2 * W/8 = 16 * 32 * 128 * 32 = 2,097,152
  const unsigned j = blockIdx.x * 256u + threadIdx.x;

  const unsigned wo = j & 31u;          // float4 index within output W row (128/4)
  const unsigned hy = (j >> 5) & 127u;  // output h
  const unsigned dz = (j >> 12) & 31u;  // output d
  const unsigned nc = j >> 17;          // n*C + c, [0,16)

  // float offset of input row (nc, d=2dz, h=2hy)
  const size_t row0 = ((size_t)nc * 64u + 2u * dz) * 256u + 2u * hy;
  const float* base = x + row0 * 256u;

  // rows: A=(d0,h0) B=(d0,h1) C=(d1,h0) D=(d1,h1); h+1 -> +256, d+1 -> +65536
  const f32x4* pA = (const f32x4*)(base) + 2u * wo;
  const f32x4* pB = (const f32x4*)(base + 256) + 2u * wo;
  const f32x4* pC = (const f32x4*)(base + 65536) + 2u * wo;
  const f32x4* pD = (const f32x4*)(base + 65536 + 256) + 2u * wo;

  const f32x4 A0 = __builtin_nontemporal_load(pA);
  const f32x4 A1 = __builtin_nontemporal_load(pA + 1);
  const f32x4 B0 = __builtin_nontemporal_load(pB);
  const f32x4 B1 = __builtin_nontemporal_load(pB + 1);
  const f32x4 C0 = __builtin_nontemporal_load(pC);
  const f32x4 C1 = __builtin_nontemporal_load(pC + 1);
  const f32x4 D0 = __builtin_nontemporal_load(pD);
  const f32x4 D1 = __builtin_nontemporal_load(pD + 1);

  // W-axis butterflies: 4 output columns per row
  // col0 <- (0,1) of q0, col1 <- (2,3) of q0, col2 <- (0,1) of q1, col3 <- (2,3) of q1
  float awl[4] = {A0[0] + A0[1], A0[2] + A0[3], A1[0] + A1[1], A1[2] + A1[3]};
  float awh[4] = {A0[0] - A0[1], A0[2] - A0[3], A1[0] - A1[1], A1[2] - A1[3]};
  float bwl[4] = {B0[0] + B0[1], B0[2] + B0[3], B1[0] + B1[1], B1[2] + B1[3]};
  float bwh[4] = {B0[0] - B0[1], B0[2] - B0[3], B1[0] - B1[1], B1[2] - B1[3]};
  float cwl[4] = {C0[0] + C0[1], C0[2] + C0[3], C1[0] + C1[1], C1[2] + C1[3]};
  float cwh[4] = {C0[0] - C0[1], C0[2] - C0[3], C1[0] - C1[1], C1[2] - C1[3]};
  float dwl[4] = {D0[0] + D0[1], D0[2] + D0[3], D1[0] + D1[1], D1[2] + D1[3]};
  float dwh[4] = {D0[0] - D0[1], D0[2] - D0[3], D1[0] - D1[1], D1[2] - D1[3]};

  f32x4 r[8];
#pragma unroll
  for (int k = 0; k < 4; ++k) {
    // H-axis
    const float d0_ll = awl[k] + bwl[k], d0_hl = awl[k] - bwl[k];
    const float d0_lh = awh[k] + bwh[k], d0_hh = awh[k] - bwh[k];
    const float d1_ll = cwl[k] + dwl[k], d1_hl = cwl[k] - dwl[k];
    const float d1_lh = cwh[k] + dwh[k], d1_hh = cwh[k] - dwh[k];
    // D-axis + scale; band = (Dhigh<<2)|(Hhigh<<1)|(Whigh)
    r[0][k] = S3 * (d0_ll + d1_ll);  // LLL
    r[1][k] = S3 * (d0_lh + d1_lh);  // LLH
    r[2][k] = S3 * (d0_hl + d1_hl);  // LHL
    r[3][k] = S3 * (d0_hh + d1_hh);  // LHH
    r[4][k] = S3 * (d0_ll - d1_ll);  // HLL
    r[5][k] = S3 * (d0_lh - d1_lh);  // HLH
    r[6][k] = S3 * (d0_hl - d1_hl);  // HHL
    r[7][k] = S3 * (d0_hh - d1_hh);  // HHH
  }

  // per-band element count = 8,388,608 floats = 2,097,152 float4; index = j
  const size_t BAND = 8388608;
#pragma unroll
  for (int b = 0; b < 8; ++b) {
    __builtin_nontemporal_store(r[b], (f32x4*)(out + (size_t)b * BAND) + j);
  }
}

extern "C" void kernel_launch(void* const* d_in, const int* in_sizes, int n_in,
                              void* d_out, int out_size, void* d_ws, size_t ws_size,
                              hipStream_t stream) {
  const float* x = (const float*)d_in[0];
  float* out = (float*)d_out;
  // 2,097,152 threads / 256 = 8192 blocks
  dwt3d_haar_kernel<<<8192, 256, 0, stream>>>(x, out);
}

// Round 4
// 84.232 us; speedup vs baseline: 1.2932x; 1.2932x over previous
//
#include <hip/hip_runtime.h>

// 3D Haar DWT, fixed size: x[N=4, C=4, D=64, H=256, W=256] f32.
// Outputs: 8 bands (LLL..HHH), each [4,4,32,128,128], concat flat in d_out.
// Band bit2=D-high, bit1=H-high, bit0=W-high; low=a+b, high=a-b per axis,
// total scale 2^-1.5.
//
// Round-4 change: the 8 band stores of one thread are 32 MiB (2^25) apart ->
// identical low address bits -> same HBM channel/bank (row-activate storm).
// De-alias: stage results in LDS and rotate the store column by 32*b within
// the block's 256-float4 window, so one thread's 8 stores differ at bit 9+.

typedef float f32x4 __attribute__((ext_vector_type(4)));

#define S3 0.35355339059327378f  // 2^-1.5

__global__ __launch_bounds__(256) void dwt3d_haar_kernel(
    const float* __restrict__ x, float* __restrict__ out) {
  // total threads = N*C * D/2 * H/2 * W/8 = 16 * 32 * 128 * 32 = 2,097,152
  const unsigned t = threadIdx.x;
  const unsigned j = blockIdx.x * 256u + t;

  const unsigned wo = j & 31u;          // float4 index within output W row (128/4)
  const unsigned hy = (j >> 5) & 127u;  // output h
  const unsigned dz = (j >> 12) & 31u;  // output d
  const unsigned nc = j >> 17;          // n*C + c, [0,16)

  // float offset of input row (nc, d=2dz, h=2hy)
  const size_t row0 = ((size_t)nc * 64u + 2u * dz) * 256u + 2u * hy;
  const float* base = x + row0 * 256u;

  // rows: A=(d0,h0) B=(d0,h1) C=(d1,h0) D=(d1,h1); h+1 -> +256, d+1 -> +65536
  const f32x4* pA = (const f32x4*)(base) + 2u * wo;
  const f32x4* pB = (const f32x4*)(base + 256) + 2u * wo;
  const f32x4* pC = (const f32x4*)(base + 65536) + 2u * wo;
  const f32x4* pD = (const f32x4*)(base + 65536 + 256) + 2u * wo;

  const f32x4 A0 = pA[0], A1 = pA[1];
  const f32x4 B0 = pB[0], B1 = pB[1];
  const f32x4 C0 = pC[0], C1 = pC[1];
  const f32x4 D0 = pD[0], D1 = pD[1];

  // W-axis butterflies: 4 output columns per row
  float awl[4] = {A0[0] + A0[1], A0[2] + A0[3], A1[0] + A1[1], A1[2] + A1[3]};
  float awh[4] = {A0[0] - A0[1], A0[2] - A0[3], A1[0] - A1[1], A1[2] - A1[3]};
  float bwl[4] = {B0[0] + B0[1], B0[2] + B0[3], B1[0] + B1[1], B1[2] + B1[3]};
  float bwh[4] = {B0[0] - B0[1], B0[2] - B0[3], B1[0] - B1[1], B1[2] - B1[3]};
  float cwl[4] = {C0[0] + C0[1], C0[2] + C0[3], C1[0] + C1[1], C1[2] + C1[3]};
  float cwh[4] = {C0[0] - C0[1], C0[2] - C0[3], C1[0] - C1[1], C1[2] - C1[3]};
  float dwl[4] = {D0[0] + D0[1], D0[2] + D0[3], D1[0] + D1[1], D1[2] + D1[3]};
  float dwh[4] = {D0[0] - D0[1], D0[2] - D0[3], D1[0] - D1[1], D1[2] - D1[3]};

  f32x4 r[8];
#pragma unroll
  for (int k = 0; k < 4; ++k) {
    const float d0_ll = awl[k] + bwl[k], d0_hl = awl[k] - bwl[k];
    const float d0_lh = awh[k] + bwh[k], d0_hh = awh[k] - bwh[k];
    const float d1_ll = cwl[k] + dwl[k], d1_hl = cwl[k] - dwl[k];
    const float d1_lh = cwh[k] + dwh[k], d1_hh = cwh[k] - dwh[k];
    r[0][k] = S3 * (d0_ll + d1_ll);  // LLL
    r[1][k] = S3 * (d0_lh + d1_lh);  // LLH
    r[2][k] = S3 * (d0_hl + d1_hl);  // LHL
    r[3][k] = S3 * (d0_hh + d1_hh);  // LHH
    r[4][k] = S3 * (d0_ll - d1_ll);  // HLL
    r[5][k] = S3 * (d0_lh - d1_lh);  // HLH
    r[6][k] = S3 * (d0_hl - d1_hl);  // HHL
    r[7][k] = S3 * (d0_hh - d1_hh);  // HHH
  }

  // Stage in LDS, then store with per-band column rotation (de-alias).
  __shared__ f32x4 stage[8][256];  // 32 KiB
#pragma unroll
  for (int b = 0; b < 8; ++b) stage[b][t] = r[b];
  __syncthreads();

  const size_t BAND = 8388608;  // floats per band
  const unsigned j0 = blockIdx.x * 256u;
#pragma unroll
  for (int bb = 0; bb < 8; ++bb) {
    const unsigned b = (bb + blockIdx.x) & 7u;          // de-phase issue order
    const unsigned tp = (t + 32u * b) & 255u;           // bijective rotation
    __builtin_nontemporal_store(
        stage[b][tp], (f32x4*)(out + (size_t)b * BAND) + (j0 + tp));
  }
}

extern "C" void kernel_launch(void* const* d_in, const int* in_sizes, int n_in,
                              void* d_out, int out_size, void* d_ws, size_t ws_size,
                              hipStream_t stream) {
  const float* x = (const float*)d_in[0];
  float* out = (float*)d_out;
  // 2,097,152 threads / 256 = 8192 blocks
  dwt3d_haar_kernel<<<8192, 256, 0, stream>>>(x, out);
}